// Round 6
// baseline (2468.405 us; speedup 1.0000x reference)
//
#include <hip/hip_runtime.h>
#include <math.h>

#define T_LEN 3000
#define EDGE 15
#define EXT_LEN 3030
#define NF 97
#define NB 64
#define NH 256
#define NI 100
#define YSTRIDE 3032   // padded ext row so (+16 floats) is 16B-aligned
#define NSEQ (NF*NB)
#define BK 120         // k_ugemm K-chunk: 3000 = 25*120
#define KC 32          // k_out K-chunk: 256 = 8*32

// ---------------- Kernel 1: filtfilt (one thread = one (f,b) sequence) ----
__global__ __launch_bounds__(64) void k_filtfilt(
    const float* __restrict__ x, const float* __restrict__ b_all,
    const float* __restrict__ a_all, const float* __restrict__ zi_all,
    float* __restrict__ Y)
{
    const int f = blockIdx.x;
    const int b = threadIdx.x;
    const double bc0 = b_all[f*5+0], bc1 = b_all[f*5+1], bc2 = b_all[f*5+2],
                 bc3 = b_all[f*5+3], bc4 = b_all[f*5+4];
    const double ac1 = a_all[f*5+1], ac2 = a_all[f*5+2],
                 ac3 = a_all[f*5+3], ac4 = a_all[f*5+4];
    const double zi0 = zi_all[f*4+0], zi1 = zi_all[f*4+1],
                 zi2 = zi_all[f*4+2], zi3 = zi_all[f*4+3];
    const float* xr = x + (size_t)b * T_LEN;
    float* y = Y + (size_t)(f * NB + b) * YSTRIDE + 1;   // ext index i lives at y[i]

    double z0, z1, z2, z3;

#define FSTEP(XV, DST) { double xv = (XV); \
    double yv = fma(bc0, xv, z0); \
    z0 = fma(bc1, xv, z1) - ac1*yv; \
    z1 = fma(bc2, xv, z2) - ac2*yv; \
    z2 = fma(bc3, xv, z3) - ac3*yv; \
    z3 = bc4*xv - ac4*yv; \
    DST = (float)yv; }

    const double x0 = (double)xr[0];
    const double xl = (double)xr[T_LEN-1];
    { const double e0 = 2.0*x0 - (double)xr[EDGE];
      z0 = zi0*e0; z1 = zi1*e0; z2 = zi2*e0; z3 = zi3*e0; }

    for (int i = 0; i < EDGE; ++i) {
        float o; FSTEP(2.0*x0 - (double)xr[EDGE - i], o); y[i] = o;
    }
    {
        float cur[20], nxt[20];
        #pragma unroll
        for (int j = 0; j < 20; ++j) cur[j] = xr[j];
        for (int k = 0; k < T_LEN; k += 20) {
            if (k + 20 < T_LEN) {
                #pragma unroll
                for (int j = 0; j < 20; ++j) nxt[j] = xr[k + 20 + j];
            }
            #pragma unroll
            for (int j = 0; j < 20; ++j) {
                float o; FSTEP((double)cur[j], o); y[EDGE + k + j] = o;
            }
            #pragma unroll
            for (int j = 0; j < 20; ++j) cur[j] = nxt[j];
        }
    }
    for (int i = 0; i < EDGE; ++i) {
        float o; FSTEP(2.0*xl - (double)xr[T_LEN - 2 - i], o); y[EDGE + T_LEN + i] = o;
    }

    const double yl = (double)y[EXT_LEN-1];
    z0 = zi0*yl; z1 = zi1*yl; z2 = zi2*yl; z3 = zi3*yl;
    {
        float bcur[20], bnxt[20];
        #pragma unroll
        for (int j = 0; j < 20; ++j) bcur[j] = y[3000 + j];
        for (int i = EXT_LEN-1; i >= 3020; --i) {
            float o; FSTEP((double)y[i], o); y[i] = o;
        }
        for (int k = 3019; k >= 19; k -= 20) {
            if (k >= 39) {
                #pragma unroll
                for (int j = 0; j < 20; ++j) bnxt[j] = y[k - 39 + j];
            }
            #pragma unroll
            for (int j = 19; j >= 0; --j) {
                float o; FSTEP((double)bcur[j], o); bcur[j] = o;
            }
            #pragma unroll
            for (int j = 0; j < 20; ++j) y[k - 19 + j] = bcur[j];
            #pragma unroll
            for (int j = 0; j < 20; ++j) bcur[j] = bnxt[j];
        }
    }
#undef FSTEP
}

// ---------------- Kernel 2: U[r][h] = (1-tanh^2(P[r]·W1[:,h]+b1))*w2 ------
__global__ __launch_bounds__(512) void k_ugemm(
    const float* __restrict__ x, const float* __restrict__ Y,
    const float* __restrict__ W1, const float* __restrict__ b1,
    const float* __restrict__ w2, float* __restrict__ U)
{
    __shared__ float Pl[2][16*BK];
    const int tid = threadIdx.x;
    const int h   = tid & 255;
    const int g   = tid >> 8;                  // 0..1 -> rows g*8..g*8+7
    const int r0  = blockIdx.x * 16;
    const float* p0;
    int pstride;
    if (r0 < NB) { p0 = x + (size_t)r0 * T_LEN;                pstride = T_LEN; }
    else         { p0 = Y + (size_t)(r0 - NB) * YSTRIDE + 16;  pstride = YSTRIDE; }

    const int rt = tid >> 5;
    const int ct = tid & 31;
    const bool stg = (ct < 30);
    const float* gsrc = p0 + (size_t)rt * pstride + ct*4;

    float acc[8] = {};
    const float* wbase = W1 + h;

    float4 v;
    if (stg) v = *(const float4*)(gsrc);       // chunk 0
    if (stg) *(float4*)&Pl[0][rt*BK + ct*4] = v;

    int cur = 0;
    for (int c = 0; c < 25; ++c) {
        float4 nxt;
        if (c < 24 && stg) nxt = *(const float4*)(gsrc + (c+1)*BK);
        __syncthreads();
        const int k0 = c * BK;
        #pragma unroll 5
        for (int k4 = 0; k4 < 30; ++k4) {
            float4 p[8];
            #pragma unroll
            for (int j = 0; j < 8; ++j)
                p[j] = *(const float4*)&Pl[cur][(g*8+j)*BK + k4*4];
            const float* wk = wbase + (size_t)(k0 + k4*4) * NH;
            float w0 = wk[0], w1v = wk[NH], w2v = wk[2*NH], w3 = wk[3*NH];
            #pragma unroll
            for (int j = 0; j < 8; ++j) acc[j] = fmaf(p[j].x, w0,  acc[j]);
            #pragma unroll
            for (int j = 0; j < 8; ++j) acc[j] = fmaf(p[j].y, w1v, acc[j]);
            #pragma unroll
            for (int j = 0; j < 8; ++j) acc[j] = fmaf(p[j].z, w2v, acc[j]);
            #pragma unroll
            for (int j = 0; j < 8; ++j) acc[j] = fmaf(p[j].w, w3,  acc[j]);
        }
        if (c < 24) {
            if (stg) *(float4*)&Pl[cur^1][rt*BK + ct*4] = nxt;
            cur ^= 1;
        }
    }
    const float b1v = b1[h], w2e = w2[h];
    #pragma unroll
    for (int j = 0; j < 8; ++j) {
        float th = tanhf(acc[j] + b1v);
        U[(size_t)(r0 + g*8 + j)*NH + h] = (1.f - th*th) * w2e;
    }
}

// ---------------- Kernel V: V[b][i][h] = 0.5*(u_row(i)+u_row(i+1)) --------
__global__ __launch_bounds__(256) void k_vbuild(
    const float* __restrict__ U, const float* __restrict__ b1,
    const float* __restrict__ w2, float* __restrict__ V)
{
    const int i = blockIdx.x;   // 0..99
    const int b = blockIdx.y;   // 0..63
    const int h = threadIdx.x;
    auto urow = [&](int ii) -> float {
        if (ii <= 2)  return U[(size_t)b*NH + h];
        if (ii <= 99) return U[(size_t)(NB + (ii-3)*NB + b)*NH + h];
        float th = tanhf(b1[h]);               // pseudo-row 100: p == 0
        return (1.f - th*th) * w2[h];
    };
    V[((size_t)b*NI + i)*NH + h] = 0.5f*(urow(i) + urow(i+1));
}

__device__ __forceinline__ float rowval(int i, int b, int t,
        const float* __restrict__ x, const float* __restrict__ Y)
{
    if (i <= 2)  return x[(size_t)b*T_LEN + t];
    if (i <= 99) return Y[(size_t)((i-3)*NB + b)*YSTRIDE + 16 + t];
    return 0.f;
}

// ---------------- Kernel 3: out[b][t][inv[i]] = (W1[t]·V[b][i]) * delta ---
// Block = (b, 256 t, 100 i); 512 threads = 8 waves; thread = 4t x 13i
// (wave i-ranges overlap by <=1, duplicate writes are identical values).
// XOR slot-swizzled LDS tiles (AST=32, slot' = slot^(row&7)): aligned b128,
// conflict-free. Single-buffered staging. K order unchanged => bit-identical.
__global__ __launch_bounds__(512, 4) void k_out(
    const float* __restrict__ x, const float* __restrict__ Y,
    const float* __restrict__ W1, const float* __restrict__ V,
    const int* __restrict__ freq_index, float* __restrict__ out)
{
    __shared__ float As[256*32];   // [row][8 slots of float4], swizzled
    __shared__ float Vs[NI*32];
    __shared__ int  inv[NI];
    const int tid = threadIdx.x;
    const int tb  = blockIdx.x;   // 0..11 (t-tile of 256)
    const int b   = blockIdx.y;   // 0..63
    if (tid < NI) inv[freq_index[tid]] = tid;

    const int lane = tid & 63;
    const int w    = tid >> 6;    // 0..7
    const int wu   = __builtin_amdgcn_readfirstlane(w);
    const int t0   = tb*256;
    const int i0   = (wu*25) >> 1;   // 0,12,25,37,50,62,75,87

    const int srow  = tid >> 3;   // 0..63
    const int sslot = tid & 7;

    float acc[4][13] = {};

    for (int c = 0; c < 8; ++c) {
        const int k0 = c * KC;
        __syncthreads();                       // prev chunk reads done
        #pragma unroll
        for (int m = 0; m < 4; ++m) {
            int row = srow + 64*m;
            int tg  = t0 + row; if (tg > T_LEN-1) tg = T_LEN-1;
            float4 v = *(const float4*)(W1 + (size_t)tg*NH + k0 + sslot*4);
            *(float4*)&As[row*32 + ((sslot ^ (row&7))<<2)] = v;
        }
        #pragma unroll
        for (int m = 0; m < 2; ++m) {
            int idx = tid + 512*m;
            if (idx < NI*8) {
                int vrow = idx >> 3, vsl = idx & 7;
                float4 v = *(const float4*)(V + ((size_t)b*NI + vrow)*NH + k0 + vsl*4);
                *(float4*)&Vs[vrow*32 + ((vsl ^ (vrow&7))<<2)] = v;
            }
        }
        __syncthreads();                       // tile ready
        #pragma unroll
        for (int k4 = 0; k4 < 8; ++k4) {
            float4 a[4];
            #pragma unroll
            for (int r = 0; r < 4; ++r) {
                int row = lane + 64*r;
                a[r] = *(const float4*)&As[row*32 + ((k4 ^ (row&7))<<2)];
            }
            #pragma unroll
            for (int jj = 0; jj < 13; ++jj) {
                int i = i0 + jj;
                float4 vv = *(const float4*)&Vs[i*32 + ((k4 ^ (i&7))<<2)];
                #pragma unroll
                for (int r = 0; r < 4; ++r) {
                    acc[r][jj] = fmaf(a[r].x, vv.x, acc[r][jj]);
                    acc[r][jj] = fmaf(a[r].y, vv.y, acc[r][jj]);
                    acc[r][jj] = fmaf(a[r].z, vv.z, acc[r][jj]);
                    acc[r][jj] = fmaf(a[r].w, vv.w, acc[r][jj]);
                }
            }
        }
    }

    // epilogue: 4 passes of 64 t through Os (reuse As region; 6464 <= 8192)
    float* Os = As;
    #pragma unroll
    for (int q = 0; q < 4; ++q) {
        const int t = t0 + q*64 + lane;
        __syncthreads();                       // As/Os region free
        if (t < T_LEN) {
            float rv = rowval(i0, b, t, x, Y);
            #pragma unroll
            for (int jj = 0; jj < 13; ++jj) {
                int i = i0 + jj;
                float rvn = rowval(i+1, b, t, x, Y);
                Os[lane*101 + inv[i]] = acc[q][jj] * (rv - rvn);
                rv = rvn;
            }
        }
        __syncthreads();
        const int tro = t0 + q*64;
        const size_t obase = ((size_t)b*T_LEN + tro) * NI;
        #pragma unroll
        for (int m = 0; m < 13; ++m) {
            int n = tid + 512*m;               // 0..6399
            if (n < 6400) {
                int t2 = n / 100;
                int j  = n - t2*100;
                if (tro + t2 < T_LEN)
                    out[obase + (size_t)t2*NI + j] = Os[t2*101 + j];
            }
        }
    }
}

extern "C" void kernel_launch(void* const* d_in, const int* in_sizes, int n_in,
                              void* d_out, int out_size, void* d_ws, size_t ws_size,
                              hipStream_t stream) {
    const float* x      = (const float*)d_in[0];
    const float* b_all  = (const float*)d_in[1];
    const float* a_all  = (const float*)d_in[2];
    const float* zi_all = (const float*)d_in[3];
    const float* W1     = (const float*)d_in[4];
    const float* b1     = (const float*)d_in[5];
    const float* w2     = (const float*)d_in[6];
    const int*   fidx   = (const int*)d_in[7];
    float* out = (float*)d_out;

    float* Y = (float*)d_ws;                         // NSEQ * YSTRIDE floats
    float* U = Y + (size_t)NSEQ * YSTRIDE;           // 6272 * 256 floats
    float* V = U + (size_t)(NB + NSEQ) * NH;         // 64*100*256 floats

    hipLaunchKernelGGL(k_filtfilt, dim3(NF), dim3(NB), 0, stream,
                       x, b_all, a_all, zi_all, Y);
    hipLaunchKernelGGL(k_ugemm, dim3((NB + NSEQ)/16), dim3(512), 0, stream,
                       x, Y, W1, b1, w2, U);
    hipLaunchKernelGGL(k_vbuild, dim3(NI, NB), dim3(NH), 0, stream,
                       U, b1, w2, V);
    hipLaunchKernelGGL(k_out, dim3((T_LEN+255)/256, NB), dim3(512), 0, stream,
                       x, Y, W1, V, fidx, out);
}

// Round 7
// 854.251 us; speedup vs baseline: 2.8896x; 2.8896x over previous
//
#include <hip/hip_runtime.h>
#include <math.h>

#define T_LEN 3000
#define EDGE 15
#define EXT_LEN 3030
#define NF 97
#define NB 64
#define NH 256
#define NI 100
#define YSTRIDE 3032   // padded ext row so (+16 floats) is 16B-aligned
#define NSEQ (NF*NB)
#define BK 120         // k_ugemm K-chunk: 3000 = 25*120
#define KC 32          // k_out K-chunk: 256 = 8*32

// ---------------- Kernel 1: filtfilt (one thread = one (f,b) sequence) ----
__global__ __launch_bounds__(64) void k_filtfilt(
    const float* __restrict__ x, const float* __restrict__ b_all,
    const float* __restrict__ a_all, const float* __restrict__ zi_all,
    float* __restrict__ Y)
{
    const int f = blockIdx.x;
    const int b = threadIdx.x;
    const double bc0 = b_all[f*5+0], bc1 = b_all[f*5+1], bc2 = b_all[f*5+2],
                 bc3 = b_all[f*5+3], bc4 = b_all[f*5+4];
    const double ac1 = a_all[f*5+1], ac2 = a_all[f*5+2],
                 ac3 = a_all[f*5+3], ac4 = a_all[f*5+4];
    const double zi0 = zi_all[f*4+0], zi1 = zi_all[f*4+1],
                 zi2 = zi_all[f*4+2], zi3 = zi_all[f*4+3];
    const float* xr = x + (size_t)b * T_LEN;
    float* y = Y + (size_t)(f * NB + b) * YSTRIDE + 1;   // ext index i lives at y[i]

    double z0, z1, z2, z3;

#define FSTEP(XV, DST) { double xv = (XV); \
    double yv = fma(bc0, xv, z0); \
    z0 = fma(bc1, xv, z1) - ac1*yv; \
    z1 = fma(bc2, xv, z2) - ac2*yv; \
    z2 = fma(bc3, xv, z3) - ac3*yv; \
    z3 = bc4*xv - ac4*yv; \
    DST = (float)yv; }

    const double x0 = (double)xr[0];
    const double xl = (double)xr[T_LEN-1];
    { const double e0 = 2.0*x0 - (double)xr[EDGE];
      z0 = zi0*e0; z1 = zi1*e0; z2 = zi2*e0; z3 = zi3*e0; }

    for (int i = 0; i < EDGE; ++i) {
        float o; FSTEP(2.0*x0 - (double)xr[EDGE - i], o); y[i] = o;
    }
    {
        float cur[20], nxt[20];
        #pragma unroll
        for (int j = 0; j < 20; ++j) cur[j] = xr[j];
        for (int k = 0; k < T_LEN; k += 20) {
            if (k + 20 < T_LEN) {
                #pragma unroll
                for (int j = 0; j < 20; ++j) nxt[j] = xr[k + 20 + j];
            }
            #pragma unroll
            for (int j = 0; j < 20; ++j) {
                float o; FSTEP((double)cur[j], o); y[EDGE + k + j] = o;
            }
            #pragma unroll
            for (int j = 0; j < 20; ++j) cur[j] = nxt[j];
        }
    }
    for (int i = 0; i < EDGE; ++i) {
        float o; FSTEP(2.0*xl - (double)xr[T_LEN - 2 - i], o); y[EDGE + T_LEN + i] = o;
    }

    const double yl = (double)y[EXT_LEN-1];
    z0 = zi0*yl; z1 = zi1*yl; z2 = zi2*yl; z3 = zi3*yl;
    {
        float bcur[20], bnxt[20];
        #pragma unroll
        for (int j = 0; j < 20; ++j) bcur[j] = y[3000 + j];
        for (int i = EXT_LEN-1; i >= 3020; --i) {
            float o; FSTEP((double)y[i], o); y[i] = o;
        }
        for (int k = 3019; k >= 19; k -= 20) {
            if (k >= 39) {
                #pragma unroll
                for (int j = 0; j < 20; ++j) bnxt[j] = y[k - 39 + j];
            }
            #pragma unroll
            for (int j = 19; j >= 0; --j) {
                float o; FSTEP((double)bcur[j], o); bcur[j] = o;
            }
            #pragma unroll
            for (int j = 0; j < 20; ++j) y[k - 19 + j] = bcur[j];
            #pragma unroll
            for (int j = 0; j < 20; ++j) bcur[j] = bnxt[j];
        }
    }
#undef FSTEP
}

// ---------------- Kernel 2: U[r][h] = (1-tanh^2(P[r]·W1[:,h]+b1))*w2 ------
__global__ __launch_bounds__(512) void k_ugemm(
    const float* __restrict__ x, const float* __restrict__ Y,
    const float* __restrict__ W1, const float* __restrict__ b1,
    const float* __restrict__ w2, float* __restrict__ U)
{
    __shared__ float Pl[2][16*BK];
    const int tid = threadIdx.x;
    const int h   = tid & 255;
    const int g   = tid >> 8;                  // 0..1 -> rows g*8..g*8+7
    const int r0  = blockIdx.x * 16;
    const float* p0;
    int pstride;
    if (r0 < NB) { p0 = x + (size_t)r0 * T_LEN;                pstride = T_LEN; }
    else         { p0 = Y + (size_t)(r0 - NB) * YSTRIDE + 16;  pstride = YSTRIDE; }

    const int rt = tid >> 5;
    const int ct = tid & 31;
    const bool stg = (ct < 30);
    const float* gsrc = p0 + (size_t)rt * pstride + ct*4;

    float acc[8] = {};
    const float* wbase = W1 + h;

    float4 v;
    if (stg) v = *(const float4*)(gsrc);       // chunk 0
    if (stg) *(float4*)&Pl[0][rt*BK + ct*4] = v;

    int cur = 0;
    for (int c = 0; c < 25; ++c) {
        float4 nxt;
        if (c < 24 && stg) nxt = *(const float4*)(gsrc + (c+1)*BK);
        __syncthreads();
        const int k0 = c * BK;
        #pragma unroll 5
        for (int k4 = 0; k4 < 30; ++k4) {
            float4 p[8];
            #pragma unroll
            for (int j = 0; j < 8; ++j)
                p[j] = *(const float4*)&Pl[cur][(g*8+j)*BK + k4*4];
            const float* wk = wbase + (size_t)(k0 + k4*4) * NH;
            float w0 = wk[0], w1v = wk[NH], w2v = wk[2*NH], w3 = wk[3*NH];
            #pragma unroll
            for (int j = 0; j < 8; ++j) acc[j] = fmaf(p[j].x, w0,  acc[j]);
            #pragma unroll
            for (int j = 0; j < 8; ++j) acc[j] = fmaf(p[j].y, w1v, acc[j]);
            #pragma unroll
            for (int j = 0; j < 8; ++j) acc[j] = fmaf(p[j].z, w2v, acc[j]);
            #pragma unroll
            for (int j = 0; j < 8; ++j) acc[j] = fmaf(p[j].w, w3,  acc[j]);
        }
        if (c < 24) {
            if (stg) *(float4*)&Pl[cur^1][rt*BK + ct*4] = nxt;
            cur ^= 1;
        }
    }
    const float b1v = b1[h], w2e = w2[h];
    #pragma unroll
    for (int j = 0; j < 8; ++j) {
        float th = tanhf(acc[j] + b1v);
        U[(size_t)(r0 + g*8 + j)*NH + h] = (1.f - th*th) * w2e;
    }
}

// ---------------- Kernel V: V[b][i][h] = 0.5*(u_row(i)+u_row(i+1)) --------
__global__ __launch_bounds__(256) void k_vbuild(
    const float* __restrict__ U, const float* __restrict__ b1,
    const float* __restrict__ w2, float* __restrict__ V)
{
    const int i = blockIdx.x;   // 0..99
    const int b = blockIdx.y;   // 0..63
    const int h = threadIdx.x;
    auto urow = [&](int ii) -> float {
        if (ii <= 2)  return U[(size_t)b*NH + h];
        if (ii <= 99) return U[(size_t)(NB + (ii-3)*NB + b)*NH + h];
        float th = tanhf(b1[h]);               // pseudo-row 100: p == 0
        return (1.f - th*th) * w2[h];
    };
    V[((size_t)b*NI + i)*NH + h] = 0.5f*(urow(i) + urow(i+1));
}

__device__ __forceinline__ float rowval(int i, int b, int t,
        const float* __restrict__ x, const float* __restrict__ Y)
{
    if (i <= 2)  return x[(size_t)b*T_LEN + t];
    if (i <= 99) return Y[(size_t)((i-3)*NB + b)*YSTRIDE + 16 + t];
    return 0.f;
}

// ---------------- Kernel 3: out[b][t][inv[i]] = (W1[t]·V[b][i]) * delta ---
// Block = (b, 128 t, 100 i); 512 threads = 8 waves.
// Wave (w>>2) owns a 64-t half (row = lane), wave (w&3) owns a 25-i quarter.
// Thread = 1t x 25i -> acc[25] only (spill-proof). Both tiles in LDS with
// XOR slot swizzle; V reads are wave-broadcast. K order unchanged =>
// bit-identical output.
__global__ __launch_bounds__(512) void k_out(
    const float* __restrict__ x, const float* __restrict__ Y,
    const float* __restrict__ W1, const float* __restrict__ V,
    const int* __restrict__ freq_index, float* __restrict__ out)
{
    __shared__ float sm[128*32 + NI*32];  // As [128][32] | Vs [100][32]
    __shared__ int  inv[NI];
    float* As = sm;
    float* Vs = sm + 128*32;
    float* Os = sm;                       // epilogue union: 64*101=6464 <= 7296
    const int tid = threadIdx.x;
    const int tb  = blockIdx.x;   // 0..23 (t-tile of 128)
    const int b   = blockIdx.y;   // 0..63
    if (tid < NI) inv[freq_index[tid]] = tid;

    const int lane = tid & 63;
    const int w    = tid >> 6;    // 0..7
    const int wu   = __builtin_amdgcn_readfirstlane(w);
    const int t0   = tb*128;
    const int tq   = wu >> 2;             // t-half 0/1
    const int i0   = (wu & 3) * 25;       // i-quarter
    const int trow = tq*64 + lane;        // my row in the A tile

    const int srow  = tid >> 3;   // 0..63
    const int sslot = tid & 7;

    float acc[25] = {};

    for (int c = 0; c < 8; ++c) {
        const int k0 = c * KC;
        __syncthreads();                       // prev chunk reads done
        #pragma unroll
        for (int m = 0; m < 2; ++m) {
            int row = srow + 64*m;
            int tg  = t0 + row; if (tg > T_LEN-1) tg = T_LEN-1;
            float4 v = *(const float4*)(W1 + (size_t)tg*NH + k0 + sslot*4);
            *(float4*)&As[row*32 + ((sslot ^ (row&7))<<2)] = v;
        }
        #pragma unroll
        for (int m = 0; m < 2; ++m) {
            int idx = tid + 512*m;
            if (idx < NI*8) {
                int vrow = idx >> 3, vsl = idx & 7;
                float4 v = *(const float4*)(V + ((size_t)b*NI + vrow)*NH + k0 + vsl*4);
                *(float4*)&Vs[vrow*32 + ((vsl ^ (vrow&7))<<2)] = v;
            }
        }
        __syncthreads();                       // tile ready
        #pragma unroll
        for (int k4 = 0; k4 < 8; ++k4) {
            float4 a = *(const float4*)&As[trow*32 + ((k4 ^ (trow&7))<<2)];
            #pragma unroll
            for (int jj = 0; jj < 25; ++jj) {
                int i = i0 + jj;
                float4 vv = *(const float4*)&Vs[i*32 + ((k4 ^ (i&7))<<2)];
                acc[jj] = fmaf(a.x, vv.x, acc[jj]);
                acc[jj] = fmaf(a.y, vv.y, acc[jj]);
                acc[jj] = fmaf(a.z, vv.z, acc[jj]);
                acc[jj] = fmaf(a.w, vv.w, acc[jj]);
            }
        }
    }

    // epilogue: two t-halves through the 64x101 Os staging buffer
    #pragma unroll
    for (int q = 0; q < 2; ++q) {
        const int t = t0 + q*64 + lane;
        __syncthreads();                       // As/Vs (Os region) free
        if (tq == q && t < T_LEN) {
            float rv = rowval(i0, b, t, x, Y);
            #pragma unroll
            for (int jj = 0; jj < 25; ++jj) {
                int i = i0 + jj;
                float rvn = rowval(i+1, b, t, x, Y);
                Os[lane*101 + inv[i]] = acc[jj] * (rv - rvn);
                rv = rvn;
            }
        }
        __syncthreads();
        const int tro = t0 + q*64;
        const size_t obase = ((size_t)b*T_LEN + tro) * NI;
        #pragma unroll
        for (int m = 0; m < 13; ++m) {
            int n = tid + 512*m;               // 0..6655
            if (n < 6400) {
                int t2 = n / 100;
                int j  = n - t2*100;
                if (tro + t2 < T_LEN)
                    out[obase + (size_t)t2*NI + j] = Os[t2*101 + j];
            }
        }
    }
}

extern "C" void kernel_launch(void* const* d_in, const int* in_sizes, int n_in,
                              void* d_out, int out_size, void* d_ws, size_t ws_size,
                              hipStream_t stream) {
    const float* x      = (const float*)d_in[0];
    const float* b_all  = (const float*)d_in[1];
    const float* a_all  = (const float*)d_in[2];
    const float* zi_all = (const float*)d_in[3];
    const float* W1     = (const float*)d_in[4];
    const float* b1     = (const float*)d_in[5];
    const float* w2     = (const float*)d_in[6];
    const int*   fidx   = (const int*)d_in[7];
    float* out = (float*)d_out;

    float* Y = (float*)d_ws;                         // NSEQ * YSTRIDE floats
    float* U = Y + (size_t)NSEQ * YSTRIDE;           // 6272 * 256 floats
    float* V = U + (size_t)(NB + NSEQ) * NH;         // 64*100*256 floats

    hipLaunchKernelGGL(k_filtfilt, dim3(NF), dim3(NB), 0, stream,
                       x, b_all, a_all, zi_all, Y);
    hipLaunchKernelGGL(k_ugemm, dim3((NB + NSEQ)/16), dim3(512), 0, stream,
                       x, Y, W1, b1, w2, U);
    hipLaunchKernelGGL(k_vbuild, dim3(NI, NB), dim3(NH), 0, stream,
                       U, b1, w2, V);
    hipLaunchKernelGGL(k_out, dim3((T_LEN+127)/128, NB), dim3(512), 0, stream,
                       x, Y, W1, V, fidx, out);
}

// Round 8
// 698.099 us; speedup vs baseline: 3.5359x; 1.2237x over previous
//
#include <hip/hip_runtime.h>
#include <math.h>

#define T_LEN 3000
#define EDGE 15
#define EXT_LEN 3030
#define NF 97
#define NB 64
#define NH 256
#define NI 100
#define YSTRIDE 3032   // padded ext row so (+16 floats) is 16B-aligned
#define NSEQ (NF*NB)
#define BK 120         // k_ugemm K-chunk: 3000 = 25*120
#define KCO 32         // k_out K-chunk: 256 = 8*32
#define LDA 132        // k_out LDS row stride (floats): pad breaks bank collisions

// ---------------- Kernel 1: filtfilt (one thread = one (f,b) sequence) ----
__global__ __launch_bounds__(64) void k_filtfilt(
    const float* __restrict__ x, const float* __restrict__ b_all,
    const float* __restrict__ a_all, const float* __restrict__ zi_all,
    float* __restrict__ Y)
{
    const int f = blockIdx.x;
    const int b = threadIdx.x;
    const double bc0 = b_all[f*5+0], bc1 = b_all[f*5+1], bc2 = b_all[f*5+2],
                 bc3 = b_all[f*5+3], bc4 = b_all[f*5+4];
    const double ac1 = a_all[f*5+1], ac2 = a_all[f*5+2],
                 ac3 = a_all[f*5+3], ac4 = a_all[f*5+4];
    const double zi0 = zi_all[f*4+0], zi1 = zi_all[f*4+1],
                 zi2 = zi_all[f*4+2], zi3 = zi_all[f*4+3];
    const float* xr = x + (size_t)b * T_LEN;
    float* y = Y + (size_t)(f * NB + b) * YSTRIDE + 1;   // ext index i lives at y[i]

    double z0, z1, z2, z3;

#define FSTEP(XV, DST) { double xv = (XV); \
    double yv = fma(bc0, xv, z0); \
    z0 = fma(bc1, xv, z1) - ac1*yv; \
    z1 = fma(bc2, xv, z2) - ac2*yv; \
    z2 = fma(bc3, xv, z3) - ac3*yv; \
    z3 = bc4*xv - ac4*yv; \
    DST = (float)yv; }

    const double x0 = (double)xr[0];
    const double xl = (double)xr[T_LEN-1];
    { const double e0 = 2.0*x0 - (double)xr[EDGE];
      z0 = zi0*e0; z1 = zi1*e0; z2 = zi2*e0; z3 = zi3*e0; }

    for (int i = 0; i < EDGE; ++i) {
        float o; FSTEP(2.0*x0 - (double)xr[EDGE - i], o); y[i] = o;
    }
    {
        float cur[20], nxt[20];
        #pragma unroll
        for (int j = 0; j < 20; ++j) cur[j] = xr[j];
        for (int k = 0; k < T_LEN; k += 20) {
            if (k + 20 < T_LEN) {
                #pragma unroll
                for (int j = 0; j < 20; ++j) nxt[j] = xr[k + 20 + j];
            }
            #pragma unroll
            for (int j = 0; j < 20; ++j) {
                float o; FSTEP((double)cur[j], o); y[EDGE + k + j] = o;
            }
            #pragma unroll
            for (int j = 0; j < 20; ++j) cur[j] = nxt[j];
        }
    }
    for (int i = 0; i < EDGE; ++i) {
        float o; FSTEP(2.0*xl - (double)xr[T_LEN - 2 - i], o); y[EDGE + T_LEN + i] = o;
    }

    const double yl = (double)y[EXT_LEN-1];
    z0 = zi0*yl; z1 = zi1*yl; z2 = zi2*yl; z3 = zi3*yl;
    {
        float bcur[20], bnxt[20];
        #pragma unroll
        for (int j = 0; j < 20; ++j) bcur[j] = y[3000 + j];
        for (int i = EXT_LEN-1; i >= 3020; --i) {
            float o; FSTEP((double)y[i], o); y[i] = o;
        }
        for (int k = 3019; k >= 19; k -= 20) {
            if (k >= 39) {
                #pragma unroll
                for (int j = 0; j < 20; ++j) bnxt[j] = y[k - 39 + j];
            }
            #pragma unroll
            for (int j = 19; j >= 0; --j) {
                float o; FSTEP((double)bcur[j], o); bcur[j] = o;
            }
            #pragma unroll
            for (int j = 0; j < 20; ++j) y[k - 19 + j] = bcur[j];
            #pragma unroll
            for (int j = 0; j < 20; ++j) bcur[j] = bnxt[j];
        }
    }
#undef FSTEP
}

// ---------------- Kernel 2: U[r][h] = (1-tanh^2(P[r]·W1[:,h]+b1))*w2 ------
__global__ __launch_bounds__(512) void k_ugemm(
    const float* __restrict__ x, const float* __restrict__ Y,
    const float* __restrict__ W1, const float* __restrict__ b1,
    const float* __restrict__ w2, float* __restrict__ U)
{
    __shared__ float Pl[2][16*BK];
    const int tid = threadIdx.x;
    const int h   = tid & 255;
    const int g   = tid >> 8;                  // 0..1 -> rows g*8..g*8+7
    const int r0  = blockIdx.x * 16;
    const float* p0;
    int pstride;
    if (r0 < NB) { p0 = x + (size_t)r0 * T_LEN;                pstride = T_LEN; }
    else         { p0 = Y + (size_t)(r0 - NB) * YSTRIDE + 16;  pstride = YSTRIDE; }

    const int rt = tid >> 5;
    const int ct = tid & 31;
    const bool stg = (ct < 30);
    const float* gsrc = p0 + (size_t)rt * pstride + ct*4;

    float acc[8] = {};
    const float* wbase = W1 + h;

    float4 v;
    if (stg) v = *(const float4*)(gsrc);       // chunk 0
    if (stg) *(float4*)&Pl[0][rt*BK + ct*4] = v;

    int cur = 0;
    for (int c = 0; c < 25; ++c) {
        float4 nxt;
        if (c < 24 && stg) nxt = *(const float4*)(gsrc + (c+1)*BK);
        __syncthreads();
        const int k0 = c * BK;
        #pragma unroll 5
        for (int k4 = 0; k4 < 30; ++k4) {
            float4 p[8];
            #pragma unroll
            for (int j = 0; j < 8; ++j)
                p[j] = *(const float4*)&Pl[cur][(g*8+j)*BK + k4*4];
            const float* wk = wbase + (size_t)(k0 + k4*4) * NH;
            float w0 = wk[0], w1v = wk[NH], w2v = wk[2*NH], w3 = wk[3*NH];
            #pragma unroll
            for (int j = 0; j < 8; ++j) acc[j] = fmaf(p[j].x, w0,  acc[j]);
            #pragma unroll
            for (int j = 0; j < 8; ++j) acc[j] = fmaf(p[j].y, w1v, acc[j]);
            #pragma unroll
            for (int j = 0; j < 8; ++j) acc[j] = fmaf(p[j].z, w2v, acc[j]);
            #pragma unroll
            for (int j = 0; j < 8; ++j) acc[j] = fmaf(p[j].w, w3,  acc[j]);
        }
        if (c < 24) {
            if (stg) *(float4*)&Pl[cur^1][rt*BK + ct*4] = nxt;
            cur ^= 1;
        }
    }
    const float b1v = b1[h], w2e = w2[h];
    #pragma unroll
    for (int j = 0; j < 8; ++j) {
        float th = tanhf(acc[j] + b1v);
        U[(size_t)(r0 + g*8 + j)*NH + h] = (1.f - th*th) * w2e;
    }
}

// ---------------- Kernel V: V[b][i][h] = 0.5*(u_row(i)+u_row(i+1)) --------
__global__ __launch_bounds__(256) void k_vbuild(
    const float* __restrict__ U, const float* __restrict__ b1,
    const float* __restrict__ w2, float* __restrict__ V)
{
    const int i = blockIdx.x;   // 0..99
    const int b = blockIdx.y;   // 0..63
    const int h = threadIdx.x;
    auto urow = [&](int ii) -> float {
        if (ii <= 2)  return U[(size_t)b*NH + h];
        if (ii <= 99) return U[(size_t)(NB + (ii-3)*NB + b)*NH + h];
        float th = tanhf(b1[h]);               // pseudo-row 100: p == 0
        return (1.f - th*th) * w2[h];
    };
    V[((size_t)b*NI + i)*NH + h] = 0.5f*(urow(i) + urow(i+1));
}

__device__ __forceinline__ float rowval(int i, int b, int t,
        const float* __restrict__ x, const float* __restrict__ Y)
{
    if (i <= 2)  return x[(size_t)b*T_LEN + t];
    if (i <= 99) return Y[(size_t)((i-3)*NB + b)*YSTRIDE + 16 + t];
    return 0.f;
}

// ---------------- Kernel 3: one 3000x6400x256 fp32 GEMM + fused epilogue --
// N = b*100+i (V is [6400][256] row-major already). Block tile 128t x 128n,
// 256 threads, thread tile 8x8 (acc=64). k-major LDS tiles [KCO][LDA]
// (staging does the transpose; reads along t/n at fixed k are conflict-free).
// Per scalar k: 4 ds_read_b128 per 64 FMA-insts (vs 26/100 before).
// Ascending-k fmaf chain per output => bit-identical to prior rounds.
__global__ __launch_bounds__(256) void k_out(
    const float* __restrict__ x, const float* __restrict__ Y,
    const float* __restrict__ W1, const float* __restrict__ V,
    const int* __restrict__ freq_index, float* __restrict__ out)
{
    __shared__ float As[KCO*LDA];   // [k][t]
    __shared__ float Vs[KCO*LDA];   // [k][n]
    __shared__ int  inv[NI];
    const int tid = threadIdx.x;
    const int tb  = blockIdx.x;     // 0..23  (t-tile of 128)
    const int nb  = blockIdx.y;     // 0..49  (n-tile of 128)
    if (tid < NI) inv[freq_index[tid]] = tid;

    const int tg = tid & 15;        // t-group (8 t each)
    const int ig = tid >> 4;        // n-group (8 n each)
    const int t0 = tb*128, n0 = nb*128;
    const int sk = tid & 7;         // staging k-slot (float4)
    const int sr = tid >> 3;        // staging row 0..31

    float acc[8][8] = {};

    for (int c = 0; c < 8; ++c) {
        const int k0 = c*KCO;
        __syncthreads();                        // prev chunk reads done
        #pragma unroll
        for (int m = 0; m < 4; ++m) {
            int row = sr + 32*m;                // 0..127
            int tg_ = t0 + row; if (tg_ > T_LEN-1) tg_ = T_LEN-1;
            float4 a = *(const float4*)(W1 + (size_t)tg_*NH + k0 + sk*4);
            As[(sk*4+0)*LDA + row] = a.x;
            As[(sk*4+1)*LDA + row] = a.y;
            As[(sk*4+2)*LDA + row] = a.z;
            As[(sk*4+3)*LDA + row] = a.w;
            float4 u = *(const float4*)(V + (size_t)(n0+row)*NH + k0 + sk*4);
            Vs[(sk*4+0)*LDA + row] = u.x;
            Vs[(sk*4+1)*LDA + row] = u.y;
            Vs[(sk*4+2)*LDA + row] = u.z;
            Vs[(sk*4+3)*LDA + row] = u.w;
        }
        __syncthreads();                        // tile ready
        #pragma unroll 4
        for (int k = 0; k < KCO; ++k) {
            float4 alo = *(const float4*)&As[k*LDA + tg*8];
            float4 ahi = *(const float4*)&As[k*LDA + tg*8 + 4];
            float4 vlo = *(const float4*)&Vs[k*LDA + ig*8];
            float4 vhi = *(const float4*)&Vs[k*LDA + ig*8 + 4];
            float a[8] = {alo.x, alo.y, alo.z, alo.w, ahi.x, ahi.y, ahi.z, ahi.w};
            float v[8] = {vlo.x, vlo.y, vlo.z, vlo.w, vhi.x, vhi.y, vhi.z, vhi.w};
            #pragma unroll
            for (int mt = 0; mt < 8; ++mt)
                #pragma unroll
                for (int nn = 0; nn < 8; ++nn)
                    acc[mt][nn] = fmaf(a[mt], v[nn], acc[mt][nn]);
        }
    }

    // fused epilogue: delta multiply + inv permutation, direct stores
    #pragma unroll
    for (int mt = 0; mt < 8; ++mt) {
        const int t = t0 + tg*8 + mt;
        if (t < T_LEN) {
            float rv = 0.f;
            #pragma unroll
            for (int nn = 0; nn < 8; ++nn) {
                const int n  = n0 + ig*8 + nn;
                const int bb = n / 100;
                const int ii = n - bb*100;
                if (nn == 0 || ii == 0) rv = rowval(ii, bb, t, x, Y);
                float rvn = rowval(ii+1, bb, t, x, Y);
                out[(size_t)bb*T_LEN*NI + (size_t)t*NI + inv[ii]]
                    = acc[mt][nn] * (rv - rvn);
                rv = rvn;
            }
        }
    }
}

extern "C" void kernel_launch(void* const* d_in, const int* in_sizes, int n_in,
                              void* d_out, int out_size, void* d_ws, size_t ws_size,
                              hipStream_t stream) {
    const float* x      = (const float*)d_in[0];
    const float* b_all  = (const float*)d_in[1];
    const float* a_all  = (const float*)d_in[2];
    const float* zi_all = (const float*)d_in[3];
    const float* W1     = (const float*)d_in[4];
    const float* b1     = (const float*)d_in[5];
    const float* w2     = (const float*)d_in[6];
    const int*   fidx   = (const int*)d_in[7];
    float* out = (float*)d_out;

    float* Y = (float*)d_ws;                         // NSEQ * YSTRIDE floats
    float* U = Y + (size_t)NSEQ * YSTRIDE;           // 6272 * 256 floats
    float* V = U + (size_t)(NB + NSEQ) * NH;         // 64*100*256 floats

    hipLaunchKernelGGL(k_filtfilt, dim3(NF), dim3(NB), 0, stream,
                       x, b_all, a_all, zi_all, Y);
    hipLaunchKernelGGL(k_ugemm, dim3((NB + NSEQ)/16), dim3(512), 0, stream,
                       x, Y, W1, b1, w2, U);
    hipLaunchKernelGGL(k_vbuild, dim3(NI, NB), dim3(NH), 0, stream,
                       U, b1, w2, V);
    hipLaunchKernelGGL(k_out, dim3((T_LEN+127)/128, (NB*NI)/128), dim3(256), 0, stream,
                       x, Y, W1, V, fidx, out);
}